// Round 1
// baseline (135.004 us; speedup 1.0000x reference)
//
#include <hip/hip_runtime.h>
#include <math.h>

// TopologicalValuePolicy — MI355X
// Structure: the 9x9x3x48 conv is 48 sparse 1-D line filters; only channels
// [0,40) are consumed, all with bias 0. For pattern p, "de" taps = -5 over
// window [4-p,8-p]; "off" taps = window-sum - 6*center. So with per-channel
// sliding window sums W[ch][p] and centers C[ch]:
//   conv[p][v=0] = 6*(W0-C0) - 5*(W0+W1+W2)
//   conv[p][v=1] = 6*(W1-C1) - 5*(W0+W1+W2)
// One block per batch element; 19x19x3 board staged into zero-padded 27x27
// channel-major LDS (no bounds checks); block reductions for softmax + value.

__global__ __launch_bounds__(256) void topo_policy_value(
    const float* __restrict__ state,
    float* __restrict__ probs,
    float* __restrict__ value)
{
    __shared__ float lin[3][27][27];
    __shared__ float red[12];

    const int tid = threadIdx.x;
    const int b = blockIdx.x;

    // zero padded tile (3*27*27 = 2187 floats)
    float* lz = &lin[0][0][0];
    #pragma unroll
    for (int i = 0; i < 9; ++i) {
        int idx = tid + i * 256;
        if (idx < 3 * 27 * 27) lz[idx] = 0.0f;
    }
    __syncthreads();

    // stage state[b] (19x19x3 NHWC) -> channel-major padded LDS
    const float* src = state + (size_t)b * (19 * 19 * 3);
    for (int j = tid; j < 19 * 19 * 3; j += 256) {
        float v = src[j];
        int y = j / 57;
        int r = j - y * 57;
        int x = r / 3;
        int c = r - x * 3;
        lin[c][y + 4][x + 4] = v;
    }
    __syncthreads();

    float fc[2] = {0.f, 0.f};   // f_cur per handled position
    float fo[2] = {0.f, 0.f};   // f_oth

    #pragma unroll
    for (int it = 0; it < 2; ++it) {
        const int pos = tid + it * 256;
        if (pos < 289) {
            const int y = pos / 17;
            const int x = pos - y * 17;

            float s0[4], s1[4];
            #pragma unroll
            for (int o = 0; o < 4; ++o) { s0[o] = 0.f; s1[o] = 0.f; }

            #pragma unroll
            for (int o = 0; o < 4; ++o) {
                float L0[9], L1[9], L2[9];
                #pragma unroll
                for (int i = 0; i < 9; ++i) {
                    int yy, xx;
                    if (o == 0)      { yy = y + 5;     xx = x + 1 + i; }
                    else if (o == 1) { yy = y + 1 + i; xx = x + 5;     }
                    else if (o == 2) { yy = y + 1 + i; xx = x + 1 + i; }
                    else             { yy = y + 1 + i; xx = x + 9 - i; }
                    L0[i] = lin[0][yy][xx];
                    L1[i] = lin[1][yy][xx];
                    L2[i] = lin[2][yy][xx];
                }
                float w0 = L0[4] + L0[5] + L0[6] + L0[7] + L0[8];
                float w1 = L1[4] + L1[5] + L1[6] + L1[7] + L1[8];
                float w2 = L2[4] + L2[5] + L2[6] + L2[7] + L2[8];
                const float C0 = L0[4], C1 = L1[4];
                #pragma unroll
                for (int p = 0; p < 5; ++p) {
                    float t  = w0 + w1 + w2;
                    float a0 = 6.f * (w0 - C0) - 5.f * t;
                    float a1 = 6.f * (w1 - C1) - 5.f * t;
                    a0 = fmaxf(a0, 0.f);
                    a1 = fmaxf(a1, 0.f);
                    float q0 = a0 * a0, q1 = a1 * a1;
                    s0[o] += q0 * q0 * q0;   // a0^6
                    s1[o] += q1 * q1 * q1;
                    if (p < 4) {
                        w0 += L0[3 - p] - L0[8 - p];
                        w1 += L1[3 - p] - L1[8 - p];
                        w2 += L2[3 - p] - L2[8 - p];
                    }
                }
            }
            float sd0 = 0.f, sd1 = 0.f;
            #pragma unroll
            for (int o = 0; o < 4; ++o) {
                sd0 += (s0[o] > 0.f) ? powf(s0[o], 5.0f / 6.0f) : 0.f;
                sd1 += (s1[o] > 0.f) ? powf(s1[o], 5.0f / 6.0f) : 0.f;
            }
            fc[it] = (sd0 > 0.f) ? powf(sd0, 0.2f) : 0.f;
            fo[it] = (sd1 > 0.f) ? powf(sd1, 0.2f) : 0.f;
        }
    }

    const bool act1 = (tid + 256) < 289;
    const float g0 = 2.f * (fc[0] + fo[0]);
    const float g1 = act1 ? 2.f * (fc[1] + fo[1]) : -3.0e38f;
    float lmax = fmaxf(g0, g1);
    float ldif = (fc[0] - fo[0]) + (fc[1] - fo[1]);   // inactive slot is 0

    #pragma unroll
    for (int off = 32; off > 0; off >>= 1) {
        lmax = fmaxf(lmax, __shfl_down(lmax, off, 64));
        ldif += __shfl_down(ldif, off, 64);
    }
    const int wave = tid >> 6;
    if ((tid & 63) == 0) { red[wave] = lmax; red[4 + wave] = ldif; }
    __syncthreads();
    if (tid == 0) {
        red[8] = fmaxf(fmaxf(red[0], red[1]), fmaxf(red[2], red[3]));
        red[9] = red[4] + red[5] + red[6] + red[7];
    }
    __syncthreads();

    const float M = red[8];
    const float e0 = expf(g0 - M);
    const float e1 = act1 ? expf(g1 - M) : 0.f;
    float lsum = e0 + e1;
    #pragma unroll
    for (int off = 32; off > 0; off >>= 1) lsum += __shfl_down(lsum, off, 64);
    if ((tid & 63) == 0) red[wave] = lsum;
    __syncthreads();
    if (tid == 0) red[10] = red[0] + red[1] + red[2] + red[3];
    __syncthreads();

    const float invS = 1.0f / red[10];
    float* pout = probs + (size_t)b * 289;
    pout[tid] = e0 * invS;
    if (act1) pout[tid + 256] = e1 * invS;
    if (tid == 0) value[b] = tanhf(red[9] * (0.2f / 32.0f));
}

extern "C" void kernel_launch(void* const* d_in, const int* in_sizes, int n_in,
                              void* d_out, int out_size, void* d_ws, size_t ws_size,
                              hipStream_t stream) {
    const float* state = (const float*)d_in[0];
    const int nb = in_sizes[0] / (19 * 19 * 3);   // 4096
    float* probs = (float*)d_out;                  // (nb, 289)
    float* value = probs + (size_t)nb * 289;       // (nb,)
    topo_policy_value<<<dim3(nb), dim3(256), 0, stream>>>(state, probs, value);
}

// Round 2
// 94.623 us; speedup vs baseline: 1.4268x; 1.4268x over previous
//
#include <hip/hip_runtime.h>
#include <math.h>

// TopologicalValuePolicy — MI355X, R2: libm powf -> hw v_log_f32/v_exp_f32.
// Structure: the 9x9x3x48 conv is 48 sparse 1-D line filters; only channels
// [0,40) are consumed, all with bias 0. For pattern p, "de" taps = -5 over
// window [4-p,8-p]; "off" taps = window-sum - 6*center:
//   conv[p][v=0] = 6*(W0-C0) - 5*(W0+W1+W2)
//   conv[p][v=1] = 6*(W1-C1) - 5*(W0+W1+W2)
// One block per batch element; 19x19x3 board staged into zero-padded 27x27
// channel-major LDS; block reductions for softmax + value.

// x >= 0 by construction; 0 -> 0. ~3 VALU ops (2 transcendental) vs ~300cyc libm powf.
__device__ __forceinline__ float fpow(float x, float e) {
    float r = __builtin_amdgcn_exp2f(e * __builtin_amdgcn_logf(x));
    return (x > 0.f) ? r : 0.f;
}
__device__ __forceinline__ float fexp(float x) {
    return __builtin_amdgcn_exp2f(x * 1.44269504088896f);
}

__global__ __launch_bounds__(256) void topo_policy_value(
    const float* __restrict__ state,
    float* __restrict__ probs,
    float* __restrict__ value)
{
    __shared__ float lin[3][27][27];
    __shared__ float red[12];

    const int tid = threadIdx.x;
    const int b = blockIdx.x;

    // zero padded tile (3*27*27 = 2187 floats)
    float* lz = &lin[0][0][0];
    #pragma unroll
    for (int i = 0; i < 9; ++i) {
        int idx = tid + i * 256;
        if (idx < 3 * 27 * 27) lz[idx] = 0.0f;
    }
    __syncthreads();

    // stage state[b] (19x19x3 NHWC) -> channel-major padded LDS
    const float* src = state + (size_t)b * (19 * 19 * 3);
    for (int j = tid; j < 19 * 19 * 3; j += 256) {
        float v = src[j];
        int y = j / 57;
        int r = j - y * 57;
        int x = r / 3;
        int c = r - x * 3;
        lin[c][y + 4][x + 4] = v;
    }
    __syncthreads();

    float fc[2] = {0.f, 0.f};   // f_cur per handled position
    float fo[2] = {0.f, 0.f};   // f_oth

    #pragma unroll
    for (int it = 0; it < 2; ++it) {
        const int pos = tid + it * 256;
        if (pos < 289) {
            const int y = pos / 17;
            const int x = pos - y * 17;

            float s0[4], s1[4];
            #pragma unroll
            for (int o = 0; o < 4; ++o) { s0[o] = 0.f; s1[o] = 0.f; }

            #pragma unroll
            for (int o = 0; o < 4; ++o) {
                float L0[9], L1[9], L2[9];
                #pragma unroll
                for (int i = 0; i < 9; ++i) {
                    int yy, xx;
                    if (o == 0)      { yy = y + 5;     xx = x + 1 + i; }
                    else if (o == 1) { yy = y + 1 + i; xx = x + 5;     }
                    else if (o == 2) { yy = y + 1 + i; xx = x + 1 + i; }
                    else             { yy = y + 1 + i; xx = x + 9 - i; }
                    L0[i] = lin[0][yy][xx];
                    L1[i] = lin[1][yy][xx];
                    L2[i] = lin[2][yy][xx];
                }
                float w0 = L0[4] + L0[5] + L0[6] + L0[7] + L0[8];
                float w1 = L1[4] + L1[5] + L1[6] + L1[7] + L1[8];
                float w2 = L2[4] + L2[5] + L2[6] + L2[7] + L2[8];
                const float C0 = L0[4], C1 = L1[4];
                #pragma unroll
                for (int p = 0; p < 5; ++p) {
                    float t  = w0 + w1 + w2;
                    float a0 = 6.f * (w0 - C0) - 5.f * t;
                    float a1 = 6.f * (w1 - C1) - 5.f * t;
                    a0 = fmaxf(a0, 0.f);
                    a1 = fmaxf(a1, 0.f);
                    float q0 = a0 * a0, q1 = a1 * a1;
                    s0[o] += q0 * q0 * q0;   // a0^6
                    s1[o] += q1 * q1 * q1;
                    if (p < 4) {
                        w0 += L0[3 - p] - L0[8 - p];
                        w1 += L1[3 - p] - L1[8 - p];
                        w2 += L2[3 - p] - L2[8 - p];
                    }
                }
            }
            float sd0 = 0.f, sd1 = 0.f;
            #pragma unroll
            for (int o = 0; o < 4; ++o) {
                sd0 += fpow(s0[o], 5.0f / 6.0f);
                sd1 += fpow(s1[o], 5.0f / 6.0f);
            }
            fc[it] = fpow(sd0, 0.2f);
            fo[it] = fpow(sd1, 0.2f);
        }
    }

    const bool act1 = (tid + 256) < 289;
    const float g0 = 2.f * (fc[0] + fo[0]);
    const float g1 = act1 ? 2.f * (fc[1] + fo[1]) : -3.0e38f;
    float lmax = fmaxf(g0, g1);
    float ldif = (fc[0] - fo[0]) + (fc[1] - fo[1]);   // inactive slot is 0

    #pragma unroll
    for (int off = 32; off > 0; off >>= 1) {
        lmax = fmaxf(lmax, __shfl_down(lmax, off, 64));
        ldif += __shfl_down(ldif, off, 64);
    }
    const int wave = tid >> 6;
    if ((tid & 63) == 0) { red[wave] = lmax; red[4 + wave] = ldif; }
    __syncthreads();
    if (tid == 0) {
        red[8] = fmaxf(fmaxf(red[0], red[1]), fmaxf(red[2], red[3]));
        red[9] = red[4] + red[5] + red[6] + red[7];
    }
    __syncthreads();

    const float M = red[8];
    const float e0 = fexp(g0 - M);
    const float e1 = act1 ? fexp(g1 - M) : 0.f;
    float lsum = e0 + e1;
    #pragma unroll
    for (int off = 32; off > 0; off >>= 1) lsum += __shfl_down(lsum, off, 64);
    if ((tid & 63) == 0) red[wave] = lsum;
    __syncthreads();
    if (tid == 0) red[10] = red[0] + red[1] + red[2] + red[3];
    __syncthreads();

    const float invS = 1.0f / red[10];
    float* pout = probs + (size_t)b * 289;
    pout[tid] = e0 * invS;
    if (act1) pout[tid + 256] = e1 * invS;
    if (tid == 0) value[b] = tanhf(red[9] * (0.2f / 32.0f));
}

extern "C" void kernel_launch(void* const* d_in, const int* in_sizes, int n_in,
                              void* d_out, int out_size, void* d_ws, size_t ws_size,
                              hipStream_t stream) {
    const float* state = (const float*)d_in[0];
    const int nb = in_sizes[0] / (19 * 19 * 3);   // 4096
    float* probs = (float*)d_out;                  // (nb, 289)
    float* value = probs + (size_t)nb * 289;       // (nb,)
    topo_policy_value<<<dim3(nb), dim3(256), 0, stream>>>(state, probs, value);
}

// Round 3
// 86.057 us; speedup vs baseline: 1.5688x; 1.0995x over previous
//
#include <hip/hip_runtime.h>
#include <math.h>

// TopologicalValuePolicy — MI355X, R3: cooperative oriented 5-sum precompute.
// conv[p][v] = 6*(Wv - Cv) - 5*(W0+W1+W2) over 5-window [p] along 4 line
// orientations. With per-cell e0 = l0-5(l1+l2), e1 = l1-5(l0+l2):
//   a_v = (5-sum of e_v along line) - 6*C_v
// Per block: stage e0/e1 (zero-padded 27x27) + centers (pre-scaled 6*l);
// one thread per (orientation,line,field) computes sliding 5-sums into G
// arrays (k-contiguous per line); each position then reads 5 contiguous G
// values per field per orientation. Strides picked for conflict-free lanes.

__device__ __forceinline__ float fpow(float x, float e) {
    float r = __builtin_amdgcn_exp2f(e * __builtin_amdgcn_logf(x));
    return (x > 0.f) ? r : 0.f;
}
__device__ __forceinline__ float fexp(float x) {
    return __builtin_amdgcn_exp2f(x * 1.44269504088896f);
}

#define OFF_E0 0        // e0 plane, 27x27
#define OFF_E1 729      // e1 plane
#define OFF_C0 1458     // 6*l0 centers, 17x17
#define OFF_C1 1747
#define OFF_GH 2036     // horizontal 5-sums: [f:357][line(17):21][k(21)]
#define OFF_GV 2750     // vertical:         [f:357][line(17):21][k(21)]
#define OFF_GD 3464     // diagonal:         [f:726][line(33):22][k(<=21)]
#define OFF_GA 4916     // anti-diagonal:    [f:693][line(33):21][k(<=21)]
#define LDS_FLOATS 6302

__global__ __launch_bounds__(256) void topo_policy_value(
    const float* __restrict__ state,
    float* __restrict__ probs,
    float* __restrict__ value)
{
    __shared__ float lds[LDS_FLOATS];
    __shared__ float red[12];

    const int tid = threadIdx.x;
    const int b = blockIdx.x;

    // zero e0/e1 padded planes (1458 floats)
    #pragma unroll
    for (int i = 0; i < 6; ++i) {
        int idx = tid + i * 256;
        if (idx < 1458) lds[idx] = 0.0f;
    }
    __syncthreads();

    // stage: one thread per board cell; compute e0,e1 + pre-scaled centers
    const float* src = state + (size_t)b * (19 * 19 * 3);
    #pragma unroll
    for (int it = 0; it < 2; ++it) {
        int j = tid + it * 256;
        if (j < 361) {
            int br = j / 19, bc = j - br * 19;
            float l0 = src[3 * j], l1 = src[3 * j + 1], l2 = src[3 * j + 2];
            float e0 = fmaf(-5.f, l1 + l2, l0);
            float e1 = fmaf(-5.f, l0 + l2, l1);
            int pi = (br + 4) * 27 + (bc + 4);
            lds[OFF_E0 + pi] = e0;
            lds[OFF_E1 + pi] = e1;
            if (br >= 1 && br <= 17 && bc >= 1 && bc <= 17) {
                int ci = (br - 1) * 17 + (bc - 1);
                lds[OFF_C0 + ci] = 6.f * l0;
                lds[OFF_C1 + ci] = 6.f * l1;
            }
        }
    }
    __syncthreads();

    // oriented sliding 5-sums: 200 threads, one per (orientation,field,line)
    if (tid < 200) {
        int t = tid, f, L;
        int base, step, outp, cnt;
        if (t < 34) {                       // horizontal: row L+5, cols 1..25
            f = t & 1; L = t >> 1;
            base = (L + 5) * 27 + 1; step = 1;
            outp = OFF_GH + f * 357 + L * 21; cnt = 21;
        } else if (t < 68) {                // vertical: col L+5, rows 1..25
            t -= 34; f = t & 1; L = t >> 1;
            base = 27 + (L + 5); step = 27;
            outp = OFF_GV + f * 357 + L * 21; cnt = 21;
        } else if (t < 134) {               // diagonal: delta = L-16
            t -= 68; f = t & 1; L = t >> 1;
            int d = L - 16;
            int j0 = (d < 0) ? -d : 0;
            base = (j0 + 1 + d) * 27 + (j0 + 1); step = 28;
            outp = OFF_GD + f * 726 + L * 22 + j0;
            cnt = 21 - ((d < 0) ? -d : d);
        } else {                            // anti-diagonal: sigma = L
            t -= 134; f = t & 1; L = t >> 1;
            int k0 = (L > 16) ? (L - 16) : 0;
            int k1 = (L + 4 < 20) ? (L + 4) : 20;
            base = 26 * k0 + 36 + L; step = 26;
            outp = OFF_GA + f * 693 + L * 21 + k0;
            cnt = k1 - k0 + 1;
        }
        const float* ef = lds + ((f == 0) ? OFF_E0 : OFF_E1);
        float s = ef[base] + ef[base + step] + ef[base + 2 * step]
                + ef[base + 3 * step] + ef[base + 4 * step];
        lds[outp] = s;
        int lo = base, hi = base + 5 * step;
        for (int i = 1; i < cnt; ++i) {
            s += ef[hi] - ef[lo];
            lo += step; hi += step;
            lds[outp + i] = s;
        }
    }
    __syncthreads();

    float fc[2] = {0.f, 0.f};
    float fo[2] = {0.f, 0.f};

    #pragma unroll
    for (int it = 0; it < 2; ++it) {
        const int pos = tid + it * 256;
        if (pos < 289) {
            const int y = pos / 17;
            const int x = pos - y * 17;
            const float h0 = lds[OFF_C0 + pos];
            const float h1 = lds[OFF_C1 + pos];

            const int bh = OFF_GH + y * 21 + x;
            const int bv = OFF_GV + x * 21 + y;
            const int bd = OFF_GD + (y - x + 16) * 22 + x;
            const int ba = OFF_GA + (y + x) * 21 + y;

            float sd0 = 0.f, sd1 = 0.f;
            #define ORIENT(B, FS)                                         \
            {                                                             \
                float t0 = 0.f, t1 = 0.f;                                 \
                _Pragma("unroll")                                         \
                for (int i = 0; i < 5; ++i) {                             \
                    float a0 = lds[(B) + i] - h0;                         \
                    float a1 = lds[(B) + (FS) + i] - h1;                  \
                    a0 = fmaxf(a0, 0.f); a1 = fmaxf(a1, 0.f);             \
                    float q0 = a0 * a0, q1 = a1 * a1;                     \
                    float m0 = q0 * q0, m1 = q1 * q1;                     \
                    t0 = fmaf(m0, q0, t0); t1 = fmaf(m1, q1, t1);         \
                }                                                         \
                sd0 += fpow(t0, 5.0f / 6.0f);                             \
                sd1 += fpow(t1, 5.0f / 6.0f);                             \
            }
            ORIENT(bh, 357)
            ORIENT(bv, 357)
            ORIENT(bd, 726)
            ORIENT(ba, 693)
            #undef ORIENT

            fc[it] = fpow(sd0, 0.2f);
            fo[it] = fpow(sd1, 0.2f);
        }
    }

    const bool act1 = (tid + 256) < 289;
    const float g0 = 2.f * (fc[0] + fo[0]);
    const float g1 = act1 ? 2.f * (fc[1] + fo[1]) : -3.0e38f;
    float lmax = fmaxf(g0, g1);
    float ldif = (fc[0] - fo[0]) + (fc[1] - fo[1]);

    #pragma unroll
    for (int off = 32; off > 0; off >>= 1) {
        lmax = fmaxf(lmax, __shfl_down(lmax, off, 64));
        ldif += __shfl_down(ldif, off, 64);
    }
    const int wave = tid >> 6;
    if ((tid & 63) == 0) { red[wave] = lmax; red[4 + wave] = ldif; }
    __syncthreads();
    if (tid == 0) {
        red[8] = fmaxf(fmaxf(red[0], red[1]), fmaxf(red[2], red[3]));
        red[9] = red[4] + red[5] + red[6] + red[7];
    }
    __syncthreads();

    const float M = red[8];
    const float e0 = fexp(g0 - M);
    const float e1 = act1 ? fexp(g1 - M) : 0.f;
    float lsum = e0 + e1;
    #pragma unroll
    for (int off = 32; off > 0; off >>= 1) lsum += __shfl_down(lsum, off, 64);
    if ((tid & 63) == 0) red[wave] = lsum;
    __syncthreads();
    if (tid == 0) red[10] = red[0] + red[1] + red[2] + red[3];
    __syncthreads();

    const float invS = 1.0f / red[10];
    float* pout = probs + (size_t)b * 289;
    pout[tid] = e0 * invS;
    if (act1) pout[tid + 256] = e1 * invS;
    if (tid == 0) value[b] = tanhf(red[9] * (0.2f / 32.0f));
}

extern "C" void kernel_launch(void* const* d_in, const int* in_sizes, int n_in,
                              void* d_out, int out_size, void* d_ws, size_t ws_size,
                              hipStream_t stream) {
    const float* state = (const float*)d_in[0];
    const int nb = in_sizes[0] / (19 * 19 * 3);   // 4096
    float* probs = (float*)d_out;                  // (nb, 289)
    float* value = probs + (size_t)nb * 289;       // (nb,)
    topo_policy_value<<<dim3(nb), dim3(256), 0, stream>>>(state, probs, value);
}